// Round 9
// baseline (978.924 us; speedup 1.0000x reference)
//
#include <hip/hip_runtime.h>
#include <hip/hip_bf16.h>
#include <cstdint>
#include <cstddef>

// tanh_max attention, B=4 H=12 S=2048 D=32, fp32 in/out. attn_mask is a
// faithful no-op in the reference -> never read.
//
// R9: BARRIER-FREE fused kernel, zero workspace.
//   R8's regression traced to 8-way LDS bank conflicts (128B K-row stride ==
//   0 mod 32 banks) + barrier/vmcnt drains. R9 removes both failure modes:
//   no __syncthreads, no global_load_lds, no shared staging. All deps are
//   VGPR deps or same-wave LDS deps (compiler-tracked waitcnts only).
//   - K: direct global->VGPR frag loads (scattered 16B/lane, permuted keys),
//     prefetched one chunk ahead. ~2x line-inflation vs coalesced: accepted.
//   - V: per-wave double-buffered LDS transpose. Loads fetch adjacent row
//     pairs so transposed writes are packed ds_write_b32 (8/chunk). Row
//     stride 36 bf16 (18 words): write banks 8(x%4)+r cover all 32 (2-way);
//     read banks 18d+4q <=2-way. Audited ACROSS lanes (R8's mistake).
//   - compute spine = R6 verified: S^T = MFMA(A=K,B=Q), P packed straight
//     into PV A-frag registers, per-lane den, 32q/wave, all 2048 keys/wave.

#define SLEN 2048
#define DK   32
#define NBH  48
#define NCH  64    // 32-key chunks
#define VROW 36    // V^T row stride in bf16 (18 words; odd word-pairs)

typedef __attribute__((ext_vector_type(8))) short bf16x8;
typedef __attribute__((ext_vector_type(4))) float f32x4;

__device__ __forceinline__ unsigned pk2(float a, float b) {
    __hip_bfloat162 h = __float22bfloat162_rn(make_float2(a, b));
    union { __hip_bfloat162 h2; unsigned u; } cv; cv.h2 = h; return cv.u;
}

__global__ __launch_bounds__(256, 3)
void attn_fused(const float* __restrict__ Q, const float* __restrict__ K,
                const float* __restrict__ V, float* __restrict__ Out) {
    // per-wave private V^T staging: [wave][buf][d 0..31][key-word 0..17]
    __shared__ __align__(16) unsigned short Vst[4][2][32 * VROW];  // 18432 B

    const int tid  = threadIdx.x;
    const int lane = tid & 63;
    const int wv   = tid >> 6;
    const int quad = lane >> 4;
    const int l16  = lane & 15;

    // XCD-aware head clustering: 6 heads per XCD.
    const int b    = blockIdx.x;       // grid = 768
    const int xcd  = b & 7;
    const int i    = b >> 3;           // 0..95
    const int bh   = xcd * 6 + (i % 6);
    const int qblk = i / 6;            // 0..15
    const int qbase = qblk * 128 + wv * 32;

    // Q frags (B operand), scaled by (1/sqrt(32))*log2(e)
    const float sc = 0.17677669529663687f * 1.4426950408889634f;
    union { bf16x8 v; unsigned u[4]; } aQ0, aQ1;
    {
        const float* qp0 = Q + ((size_t)bh * SLEN + qbase + l16) * DK + quad * 8;
        float4 qa = *(const float4*)qp0;
        float4 qb = *(const float4*)(qp0 + 4);
        aQ0.u[0] = pk2(qa.x * sc, qa.y * sc); aQ0.u[1] = pk2(qa.z * sc, qa.w * sc);
        aQ0.u[2] = pk2(qb.x * sc, qb.y * sc); aQ0.u[3] = pk2(qb.z * sc, qb.w * sc);
        const float* qp1 = qp0 + 16 * DK;
        float4 qc = *(const float4*)qp1;
        float4 qd = *(const float4*)(qp1 + 4);
        aQ1.u[0] = pk2(qc.x * sc, qc.y * sc); aQ1.u[1] = pk2(qc.z * sc, qc.w * sc);
        aQ1.u[2] = pk2(qd.x * sc, qd.y * sc); aQ1.u[3] = pk2(qd.z * sc, qd.w * sc);
    }

    const float* Kh = K + (size_t)bh * SLEN * DK;
    const float* Vh = V + (size_t)bh * SLEN * DK;

    // K frag source: lane (quad,l16), tile t: key = 8*(l16>>2)+2*(l16&3)+t,
    // floats [quad*8 .. +7].  kp covers tile0-lo; +4 = hi; +DK = tile1.
    const int keyl = 8 * (l16 >> 2) + 2 * (l16 & 3);
    const float* kp = Kh + (size_t)keyl * DK + quad * 8;

    // V staging source: lane covers rows {2vr, 2vr+1, 16+2vr, 17+2vr},
    // cols [4vc .. 4vc+3]  (adjacent-row pairs -> packed b32 writes).
    const int vr = lane >> 3;          // 0..7
    const int vc = lane & 7;           // 0..7
    const float* vp = Vh + (size_t)(2 * vr) * DK + vc * 4;

    f32x4 o00 = {0,0,0,0}, o01 = {0,0,0,0};   // q-tile0: O[q=quad*4+r][d=l16 / 16+l16]
    f32x4 o10 = {0,0,0,0}, o11 = {0,0,0,0};   // q-tile1
    float den0 = 0.f, den1 = 0.f;             // per-lane: q = l16 (+16)
    const f32x4 zero = {0,0,0,0};

    unsigned*             Vw = (unsigned*)&Vst[wv][0][0];   // buf stride 32*18 words
    const unsigned short* Vr = &Vst[wv][0][0];

    // ---- prologue: K(0) + V(0) -> buf0 ----
    float4 ka0 = *(const float4*)(kp);
    float4 ka1 = *(const float4*)(kp + 4);
    float4 kb0 = *(const float4*)(kp + DK);
    float4 kb1 = *(const float4*)(kp + DK + 4);
    {
        float4 va0 = *(const float4*)(vp);
        float4 vb0 = *(const float4*)(vp + DK);
        float4 va1 = *(const float4*)(vp + 16 * DK);
        float4 vb1 = *(const float4*)(vp + 17 * DK);
        Vw[(4*vc + 0) * 18 + vr]     = pk2(va0.x, vb0.x);
        Vw[(4*vc + 1) * 18 + vr]     = pk2(va0.y, vb0.y);
        Vw[(4*vc + 2) * 18 + vr]     = pk2(va0.z, vb0.z);
        Vw[(4*vc + 3) * 18 + vr]     = pk2(va0.w, vb0.w);
        Vw[(4*vc + 0) * 18 + 8 + vr] = pk2(va1.x, vb1.x);
        Vw[(4*vc + 1) * 18 + 8 + vr] = pk2(va1.y, vb1.y);
        Vw[(4*vc + 2) * 18 + 8 + vr] = pk2(va1.z, vb1.z);
        Vw[(4*vc + 3) * 18 + 8 + vr] = pk2(va1.w, vb1.w);
    }

    #pragma unroll 2
    for (int c = 0; c < NCH; ++c) {
        const int buf  = c & 1;
        const int nbuf = buf ^ 1;

        // prefetch chunk c+1 (K frags + V rows) into VGPRs
        float4 nka0, nka1, nkb0, nkb1, nva0, nvb0, nva1, nvb1;
        if (c + 1 < NCH) {
            const float* kc = kp + (size_t)(c + 1) * 1024;
            nka0 = *(const float4*)(kc);
            nka1 = *(const float4*)(kc + 4);
            nkb0 = *(const float4*)(kc + DK);
            nkb1 = *(const float4*)(kc + DK + 4);
            const float* vcp = vp + (size_t)(c + 1) * 1024;
            nva0 = *(const float4*)(vcp);
            nvb0 = *(const float4*)(vcp + DK);
            nva1 = *(const float4*)(vcp + 16 * DK);
            nvb1 = *(const float4*)(vcp + 17 * DK);
        }

        // pack current K frags
        union { bf16x8 v; unsigned u[4]; } kf0, kf1;
        kf0.u[0] = pk2(ka0.x, ka0.y); kf0.u[1] = pk2(ka0.z, ka0.w);
        kf0.u[2] = pk2(ka1.x, ka1.y); kf0.u[3] = pk2(ka1.z, ka1.w);
        kf1.u[0] = pk2(kb0.x, kb0.y); kf1.u[1] = pk2(kb0.z, kb0.w);
        kf1.u[2] = pk2(kb1.x, kb1.y); kf1.u[3] = pk2(kb1.z, kb1.w);

        // S^T tiles: A=K (rows=keys), B=Q (cols=queries)
        f32x4 s00 = __builtin_amdgcn_mfma_f32_16x16x32_bf16(kf0.v, aQ0.v, zero, 0, 0, 0);
        f32x4 s01 = __builtin_amdgcn_mfma_f32_16x16x32_bf16(kf1.v, aQ0.v, zero, 0, 0, 0);
        f32x4 s10 = __builtin_amdgcn_mfma_f32_16x16x32_bf16(kf0.v, aQ1.v, zero, 0, 0, 0);
        f32x4 s11 = __builtin_amdgcn_mfma_f32_16x16x32_bf16(kf1.v, aQ1.v, zero, 0, 0, 0);

        // exp + pack straight into PV A-frags (keys 8*quad+2r, +1)
        union { bf16x8 v; unsigned u[4]; } aP0, aP1;
        #pragma unroll
        for (int r = 0; r < 4; ++r) {
            float e0  = __builtin_amdgcn_exp2f(s00[r]);
            float en0 = __builtin_amdgcn_exp2f(-s00[r]);
            float e1  = __builtin_amdgcn_exp2f(s01[r]);
            float en1 = __builtin_amdgcn_exp2f(-s01[r]);
            den0 += (e0 + en0) + (e1 + en1);
            aP0.u[r] = pk2(e0 - en0, e1 - en1);
        }
        #pragma unroll
        for (int r = 0; r < 4; ++r) {
            float e0  = __builtin_amdgcn_exp2f(s10[r]);
            float en0 = __builtin_amdgcn_exp2f(-s10[r]);
            float e1  = __builtin_amdgcn_exp2f(s11[r]);
            float en1 = __builtin_amdgcn_exp2f(-s11[r]);
            den1 += (e0 + en0) + (e1 + en1);
            aP1.u[r] = pk2(e0 - en0, e1 - en1);
        }

        // V^T frags from this wave's buf (written a full chunk ago)
        const unsigned short* vt = Vr + buf * (32 * VROW);
        union { bf16x8 v; uint2 h[2]; } V0, V1;
        V0.h[0] = *(const uint2*)(vt + VROW * l16 + 8 * quad);
        V0.h[1] = *(const uint2*)(vt + VROW * l16 + 8 * quad + 4);
        V1.h[0] = *(const uint2*)(vt + VROW * (16 + l16) + 8 * quad);
        V1.h[1] = *(const uint2*)(vt + VROW * (16 + l16) + 8 * quad + 4);

        // PV
        o00 = __builtin_amdgcn_mfma_f32_16x16x32_bf16(aP0.v, V0.v, o00, 0, 0, 0);
        o01 = __builtin_amdgcn_mfma_f32_16x16x32_bf16(aP0.v, V1.v, o01, 0, 0, 0);
        o10 = __builtin_amdgcn_mfma_f32_16x16x32_bf16(aP1.v, V0.v, o10, 0, 0, 0);
        o11 = __builtin_amdgcn_mfma_f32_16x16x32_bf16(aP1.v, V1.v, o11, 0, 0, 0);

        // convert + transpose-write V(c+1) into nbuf; roll K regs
        if (c + 1 < NCH) {
            unsigned* vw = Vw + nbuf * (32 * 18);
            vw[(4*vc + 0) * 18 + vr]     = pk2(nva0.x, nvb0.x);
            vw[(4*vc + 1) * 18 + vr]     = pk2(nva0.y, nvb0.y);
            vw[(4*vc + 2) * 18 + vr]     = pk2(nva0.z, nvb0.z);
            vw[(4*vc + 3) * 18 + vr]     = pk2(nva0.w, nvb0.w);
            vw[(4*vc + 0) * 18 + 8 + vr] = pk2(nva1.x, nvb1.x);
            vw[(4*vc + 1) * 18 + 8 + vr] = pk2(nva1.y, nvb1.y);
            vw[(4*vc + 2) * 18 + 8 + vr] = pk2(nva1.z, nvb1.z);
            vw[(4*vc + 3) * 18 + 8 + vr] = pk2(nva1.w, nvb1.w);
            ka0 = nka0; ka1 = nka1; kb0 = nkb0; kb1 = nkb1;
        }
    }

    // den: reduce across quads (each quad covered keys 8q..8q+7 per chunk)
    den0 += __shfl_xor(den0, 16); den0 += __shfl_xor(den0, 32);
    den1 += __shfl_xor(den1, 16); den1 += __shfl_xor(den1, 32);

    float* outp = Out + ((size_t)bh * SLEN + qbase) * DK;
    #pragma unroll
    for (int rr = 0; rr < 4; ++rr) {
        float inv0 = 1.0f / __shfl(den0, quad * 4 + rr, 16);
        float inv1 = 1.0f / __shfl(den1, quad * 4 + rr, 16);
        int q0 = quad * 4 + rr;
        int q1 = 16 + quad * 4 + rr;
        outp[(size_t)q0 * DK + l16]      = o00[rr] * inv0;
        outp[(size_t)q0 * DK + 16 + l16] = o01[rr] * inv0;
        outp[(size_t)q1 * DK + l16]      = o10[rr] * inv1;
        outp[(size_t)q1 * DK + 16 + l16] = o11[rr] * inv1;
    }
}

extern "C" void kernel_launch(void* const* d_in, const int* in_sizes, int n_in,
                              void* d_out, int out_size, void* d_ws, size_t ws_size,
                              hipStream_t stream) {
    const float* Q = (const float*)d_in[0];
    const float* K = (const float*)d_in[1];
    const float* V = (const float*)d_in[2];
    // d_in[3] = attn_mask: no-op in reference, never read. d_ws: unused.
    float* Out = (float*)d_out;
    attn_fused<<<dim3(NBH * 16), dim3(256), 0, stream>>>(Q, K, V, Out);
}